// Round 1
// baseline (153.818 us; speedup 1.0000x reference)
//
#include <hip/hip_runtime.h>
#include <hip/hip_bf16.h>
#include <math.h>

// DETR HungarianMatcher cost matrix:
// cost[b,q,j] = 5*L1(pred_box, tgt_box) - softmax(logits)[tgt_label[j]] - 2*GIoU
// B=16, Q=900, C=92, T=1600 -> out [16,900,1600] fp32 (92.2 MB)

#define TMAX 1600
#define CMAX 128
#define NTHR 256

__global__ __launch_bounds__(NTHR) void detr_cost_kernel(
    const float* __restrict__ logits,   // [BQ, C]
    const float* __restrict__ pboxes,   // [BQ, 4] cxcywh
    const int*   __restrict__ labels,   // [T]
    const float* __restrict__ tboxes,   // [T, 4] cxcywh
    float*       __restrict__ out,      // [BQ, T]
    int C, int T)
{
    __shared__ float4 s_tb[TMAX];   // target cxcywh
    __shared__ float  s_ta[TMAX];   // target area (w*h)
    __shared__ int    s_tl[TMAX];   // target label
    __shared__ float  s_e[CMAX];    // exp(logit - max) for this row
    __shared__ float  s_inv;        // 1 / sum(exp)

    const int i   = blockIdx.x;     // row = b*Q + q
    const int tid = threadIdx.x;

    // ---- stage targets into LDS (coalesced, once per block) ----
    const float4* tb4 = (const float4*)tboxes;
    for (int j = tid; j < T; j += NTHR) {
        float4 t = tb4[j];
        s_tb[j] = t;
        s_ta[j] = t.z * t.w;
        s_tl[j] = labels[j];
    }

    // ---- softmax of this row's logits: wave 0 only, shuffle reduce ----
    if (tid < 64) {
        float v1 = (tid < C)      ? logits[(long long)i * C + tid]      : -INFINITY;
        float v2 = (tid + 64 < C) ? logits[(long long)i * C + tid + 64] : -INFINITY;
        float m = fmaxf(v1, v2);
        #pragma unroll
        for (int o = 32; o > 0; o >>= 1) m = fmaxf(m, __shfl_xor(m, o));
        float e1 = (tid < C)      ? __expf(v1 - m) : 0.0f;
        float e2 = (tid + 64 < C) ? __expf(v2 - m) : 0.0f;
        float s = e1 + e2;
        #pragma unroll
        for (int o = 32; o > 0; o >>= 1) s += __shfl_xor(s, o);
        if (tid < C)      s_e[tid]      = e1;
        if (tid + 64 < C) s_e[tid + 64] = e2;
        if (tid == 0)     s_inv = 1.0f / s;
    }

    __syncthreads();

    // ---- pred-side values (uniform across block -> scalar regs) ----
    const float4 pb = ((const float4*)pboxes)[i];
    const float pcx = pb.x, pcy = pb.y, pw = pb.z, ph = pb.w;
    const float px1 = pcx - 0.5f * pw;
    const float py1 = pcy - 0.5f * ph;
    const float px2 = pcx + 0.5f * pw;
    const float py2 = pcy + 0.5f * ph;
    const float pa  = pw * ph;
    const float inv = s_inv;

    // ---- main loop: 4 consecutive targets per thread, float4 stores ----
    float4* out4 = (float4*)(out + (long long)i * T);
    const int V = T >> 2;
    for (int v = tid; v < V; v += NTHR) {
        float4 r;
        float* rp = (float*)&r;
        #pragma unroll
        for (int u = 0; u < 4; ++u) {
            const int j = 4 * v + u;
            const float4 t = s_tb[j];

            // L1 on cxcywh
            float l1 = fabsf(pcx - t.x) + fabsf(pcy - t.y)
                     + fabsf(pw  - t.z) + fabsf(ph  - t.w);

            // target xyxy
            float tx1 = t.x - 0.5f * t.z;
            float ty1 = t.y - 0.5f * t.w;
            float tx2 = t.x + 0.5f * t.z;
            float ty2 = t.y + 0.5f * t.w;
            float ta  = s_ta[j];

            // intersection
            float ltx = fmaxf(px1, tx1), lty = fmaxf(py1, ty1);
            float rbx = fminf(px2, tx2), rby = fminf(py2, ty2);
            float iw = fmaxf(rbx - ltx, 0.0f);
            float ih = fmaxf(rby - lty, 0.0f);
            float inter = iw * ih;
            float uni = pa + ta - inter;
            float iou = inter * __builtin_amdgcn_rcpf(uni);

            // enclosing box
            float ex1 = fminf(px1, tx1), ey1 = fminf(py1, ty1);
            float ex2 = fmaxf(px2, tx2), ey2 = fmaxf(py2, ty2);
            float ew = fmaxf(ex2 - ex1, 0.0f);
            float eh = fmaxf(ey2 - ey1, 0.0f);
            float ea = ew * eh;
            float giou = iou - (ea - uni) * __builtin_amdgcn_rcpf(ea);

            // class cost: -prob[label]
            float prob = s_e[s_tl[j]] * inv;

            rp[u] = 5.0f * l1 - prob - 2.0f * giou;
        }
        out4[v] = r;
    }
}

extern "C" void kernel_launch(void* const* d_in, const int* in_sizes, int n_in,
                              void* d_out, int out_size, void* d_ws, size_t ws_size,
                              hipStream_t stream) {
    const float* logits = (const float*)d_in[0];   // [B,Q,C]
    const float* pboxes = (const float*)d_in[1];   // [B,Q,4]
    const int*   labels = (const int*)d_in[2];     // [T]
    const float* tboxes = (const float*)d_in[3];   // [T,4]
    float* out = (float*)d_out;

    const int T  = in_sizes[2];
    const int BQ = in_sizes[1] / 4;
    const int C  = in_sizes[0] / BQ;

    detr_cost_kernel<<<BQ, NTHR, 0, stream>>>(logits, pboxes, labels, tboxes, out, C, T);
}

// Round 2
// 127.393 us; speedup vs baseline: 1.2074x; 1.2074x over previous
//
#include <hip/hip_runtime.h>
#include <hip/hip_bf16.h>
#include <math.h>

// DETR HungarianMatcher cost matrix:
// cost[b,q,j] = 5*L1(pred_box, tgt_box) - softmax(logits)[tgt_label[j]] - 2*GIoU
// Shapes: B=16, Q=900, C=92, T=1600 -> out [B*Q, T] fp32 (92.2 MB)
//
// Structure: block = 256 thr, handles R=16 rows x TT=800 targets.
//   grid = (BQ/R = 900, T/TT = 2).
//   Targets staged ONCE per block in SoA xyxy layout -> conflict-free
//   ds_read_b128 (round 1's AoS float4 was ~32-way bank conflicted, 8.3M cyc).
//   Softmax per row premultiplied+negated so class cost = one LDS gather.

#define RQ   16     // rows per block
#define TT   800    // targets per block
#define GG   200    // float4 groups per block (TT/4)
#define NTHR 256
#define CC   92     // classes
#define CP   96     // padded class stride (96 % 32 == 0; bank = label % 32)

__global__ __launch_bounds__(NTHR) void detr_cost_kernel(
    const float* __restrict__ logits,   // [BQ, C]
    const float* __restrict__ pboxes,   // [BQ, 4] cxcywh
    const int*   __restrict__ labels,   // [T]
    const float* __restrict__ tboxes,   // [T, 4] cxcywh
    float*       __restrict__ out,      // [BQ, T]
    int T)
{
    __shared__ alignas(16) float s_tx1[TT];
    __shared__ alignas(16) float s_ty1[TT];
    __shared__ alignas(16) float s_tx2[TT];
    __shared__ alignas(16) float s_ty2[TT];
    __shared__ alignas(16) int   s_lbl[TT];
    __shared__ float4 s_pbox[RQ];        // pred xyxy per row
    __shared__ float  s_parea[RQ];       // pred area per row
    __shared__ float  s_nprob[RQ * CP];  // -softmax(logits) per row

    const int tid  = threadIdx.x;
    const int row0 = blockIdx.x * RQ;    // base row (b*Q+q)
    const int tb   = blockIdx.y * TT;    // base target

    // ---- stage targets (SoA xyxy), once per block ----
    const float4* tb4 = (const float4*)tboxes;
    for (int j = tid; j < TT; j += NTHR) {
        float4 t = tb4[tb + j];
        s_tx1[j] = t.x - 0.5f * t.z;
        s_ty1[j] = t.y - 0.5f * t.w;
        s_tx2[j] = t.x + 0.5f * t.z;
        s_ty2[j] = t.y + 0.5f * t.w;
        s_lbl[j] = labels[tb + j];
    }

    // ---- pred rows: xyxy + area ----
    if (tid < RQ) {
        float4 p = ((const float4*)pboxes)[row0 + tid];
        float x1 = p.x - 0.5f * p.z, y1 = p.y - 0.5f * p.w;
        float x2 = p.x + 0.5f * p.z, y2 = p.y + 0.5f * p.w;
        s_pbox[tid]  = make_float4(x1, y1, x2, y2);
        s_parea[tid] = (x2 - x1) * (y2 - y1);
    }

    // ---- softmax: wave w handles rows w, w+4, w+8, w+12 ----
    const int wv = tid >> 6, ln = tid & 63;
    for (int rr = wv; rr < RQ; rr += 4) {
        const float* lg = logits + (long long)(row0 + rr) * CC;
        float v1 = (ln < CC)      ? lg[ln]      : -INFINITY;
        float v2 = (ln + 64 < CC) ? lg[ln + 64] : -INFINITY;
        float m = fmaxf(v1, v2);
        #pragma unroll
        for (int o = 32; o > 0; o >>= 1) m = fmaxf(m, __shfl_xor(m, o));
        float e1 = (ln < CC)      ? __expf(v1 - m) : 0.0f;
        float e2 = (ln + 64 < CC) ? __expf(v2 - m) : 0.0f;
        float s = e1 + e2;
        #pragma unroll
        for (int o = 32; o > 0; o >>= 1) s += __shfl_xor(s, o);
        float inv = __builtin_amdgcn_rcpf(s);
        if (ln < CC)      s_nprob[rr * CP + ln]      = -e1 * inv;
        if (ln + 64 < CC) s_nprob[rr * CP + ln + 64] = -e2 * inv;
    }

    __syncthreads();

    // ---- main loop: RQ*GG = 3200 work items, group-fastest flatten ----
    for (int w = tid; w < RQ * GG; w += NTHR) {
        const int row = w / GG;          // compile-time divisor -> magic mul
        const int g   = w - row * GG;

        const float4 pb = s_pbox[row];   // broadcast-ish LDS read
        const float  pa = s_parea[row];
        const float* np = &s_nprob[row * CP];

        // conflict-free b128 SoA reads: 4 consecutive targets
        const float4 tx1 = *(const float4*)&s_tx1[4 * g];
        const float4 ty1 = *(const float4*)&s_ty1[4 * g];
        const float4 tx2 = *(const float4*)&s_tx2[4 * g];
        const float4 ty2 = *(const float4*)&s_ty2[4 * g];
        const int4   lb  = *(const int4*)&s_lbl[4 * g];

        const float* fx1 = (const float*)&tx1;
        const float* fy1 = (const float*)&ty1;
        const float* fx2 = (const float*)&tx2;
        const float* fy2 = (const float*)&ty2;
        const int*   flb = (const int*)&lb;

        float4 r;
        float* rp = (float*)&r;
        #pragma unroll
        for (int u = 0; u < 4; ++u) {
            const float x1 = fx1[u], y1 = fy1[u], x2 = fx2[u], y2 = fy2[u];

            // L1 on cxcywh, reconstructed from xyxy diffs
            const float d1 = pb.x - x1, d2 = pb.z - x2;
            const float e1 = pb.y - y1, e2 = pb.w - y2;
            const float l1 = 0.5f * (fabsf(d1 + d2) + fabsf(e1 + e2))
                           + fabsf(d2 - d1) + fabsf(e2 - e1);

            // IoU
            const float ta    = (x2 - x1) * (y2 - y1);
            const float iw    = fminf(pb.z, x2) - fmaxf(pb.x, x1);
            const float ih    = fminf(pb.w, y2) - fmaxf(pb.y, y1);
            const float inter = fmaxf(iw, 0.0f) * fmaxf(ih, 0.0f);
            const float uni   = pa + ta - inter;
            const float iou   = inter * __builtin_amdgcn_rcpf(uni);

            // enclosing box (always non-negative extents)
            const float ew   = fmaxf(pb.z, x2) - fminf(pb.x, x1);
            const float eh   = fmaxf(pb.w, y2) - fminf(pb.y, y1);
            const float ea   = ew * eh;
            const float giou = iou - (ea - uni) * __builtin_amdgcn_rcpf(ea);

            // cost = 5*L1 - prob - 2*giou   (np already holds -prob)
            rp[u] = fmaf(5.0f, l1, np[flb[u]]) - 2.0f * giou;
        }

        *(float4*)(out + (long long)(row0 + row) * T + tb + 4 * g) = r;
    }
}

extern "C" void kernel_launch(void* const* d_in, const int* in_sizes, int n_in,
                              void* d_out, int out_size, void* d_ws, size_t ws_size,
                              hipStream_t stream) {
    const float* logits = (const float*)d_in[0];   // [B,Q,C]
    const float* pboxes = (const float*)d_in[1];   // [B,Q,4]
    const int*   labels = (const int*)d_in[2];     // [T]
    const float* tboxes = (const float*)d_in[3];   // [T,4]
    float* out = (float*)d_out;

    const int T  = in_sizes[2];        // 1600
    const int BQ = in_sizes[1] / 4;    // 14400

    dim3 grid(BQ / RQ, T / TT);        // (900, 2)
    detr_cost_kernel<<<grid, NTHR, 0, stream>>>(logits, pboxes, labels, tboxes, out, T);
}